// Round 12
// baseline (299.621 us; speedup 1.0000x reference)
//
#include <hip/hip_runtime.h>
#include <stdint.h>

#define E_  8
#define H_  768
#define I_  1152
#define T_  4096
#define F2_ (2*I_)   // 2304

typedef unsigned short u16;
typedef __attribute__((ext_vector_type(8))) __bf16 bf16x8;
typedef __attribute__((ext_vector_type(4))) float floatx4;

typedef const void __attribute__((address_space(1))) as1_void;
typedef void __attribute__((address_space(3))) as3_void;

__device__ __forceinline__ void gld16(void* lds, const void* g) {
  __builtin_amdgcn_global_load_lds((as1_void*)g, (as3_void*)lds, 16, 0, 0);
}

__device__ __forceinline__ u16 f2bf(float f) {
  union { float f; unsigned int i; } v; v.f = f;
  unsigned int r = v.i + 0x7FFF + ((v.i >> 16) & 1);  // round-to-nearest-even
  return (u16)(r >> 16);
}

__device__ __forceinline__ float bf2f(u16 u) {
  union { unsigned int i; float f; } v; v.i = ((unsigned int)u) << 16;
  return v.f;
}

// Vectorized transpose+convert core (G13): float4 reads, ushort4 LDS writes (pad 68
// keeps 8B row alignment), ushort4 global stores.  Caller provides the LDS tile.
__device__ __forceinline__ void transpose_core(u16 (*tile)[68],
                                               const float* __restrict__ src,
                                               u16* __restrict__ dst,
                                               int R, int C, int xi, int yi, int zi) {
  const float* s = src + (long)zi * R * C;
  u16*         d = dst + (long)zi * R * C;
  int r0 = yi * 64, c0 = xi * 64;
  int c4 = (threadIdx.x & 15) * 4;        // col offset 0..60
  int rr = threadIdx.x >> 4;              // row 0..15
  #pragma unroll
  for (int k = 0; k < 64; k += 16) {
    float4 v = *(const float4*)(s + (long)(r0 + rr + k) * C + (c0 + c4));
    ushort4 u;
    u.x = f2bf(v.x); u.y = f2bf(v.y); u.z = f2bf(v.z); u.w = f2bf(v.w);
    *(ushort4*)&tile[rr + k][c4] = u;
  }
  __syncthreads();
  int c  = threadIdx.x >> 2;              // 0..63
  int rq = (threadIdx.x & 3) * 4;         // 0,4,8,12
  #pragma unroll
  for (int k = 0; k < 64; k += 16) {
    ushort4 u;
    u.x = tile[rq + k + 0][c];
    u.y = tile[rq + k + 1][c];
    u.z = tile[rq + k + 2][c];
    u.w = tile[rq + k + 3][c];
    *(ushort4*)(d + (long)(c0 + c) * R + (r0 + rq + k)) = u;
  }
}

// ====== fused prep: gate + convert sWi/sWo + transpose Wi (Wo transpose lives in g1) ===
#define GATE_BLKS (T_ / 4)                              // 1024
#define CONV_BLKS ((F2_ * H_ + H_ * I_) / 1024)         // 2592
#define TWI_X (F2_ / 64)                                // 36
#define TWI_Y (H_ / 64)                                 // 12
#define TWI_BLKS (TWI_X * TWI_Y * E_)                   // 3456
#define TWO_X (H_ / 64)                                 // 12
#define TWO_Y (I_ / 64)                                 // 18
#define TWO_BLKS (TWO_X * TWO_Y * E_)                   // 1728 (runs inside g1's grid)
#define PREP_BLKS (GATE_BLKS + CONV_BLKS + TWI_BLKS)

__global__ __launch_bounds__(256)
void prep_all(const float* __restrict__ x, const float* __restrict__ gw,
              const float* __restrict__ bias,
              int* __restrict__ top2e, float* __restrict__ top2w, u16* __restrict__ xb,
              const float* __restrict__ sWi, u16* __restrict__ sWib,
              const float* __restrict__ sWo, u16* __restrict__ sWob,
              const float* __restrict__ Wi, u16* __restrict__ WiT) {
  __shared__ u16 tile[64][68];
  int b = blockIdx.x;
  if (b < GATE_BLKS) {
    int t    = b * 4 + (threadIdx.x >> 6);
    int lane = threadIdx.x & 63;
    float acc[E_];
    #pragma unroll
    for (int e = 0; e < E_; e++) acc[e] = 0.f;
    #pragma unroll
    for (int i = 0; i < H_ / 256; i++) {
      int c = i * 256 + lane * 4;
      float4 xv = *(const float4*)(x + (long)t * H_ + c);
      ushort4 u;
      u.x = f2bf(xv.x); u.y = f2bf(xv.y); u.z = f2bf(xv.z); u.w = f2bf(xv.w);
      *(ushort4*)(xb + (long)t * H_ + c) = u;
      #pragma unroll
      for (int e = 0; e < E_; e++) {
        float4 g = *(const float4*)(gw + e * H_ + c);
        acc[e] += xv.x * g.x + xv.y * g.y + xv.z * g.z + xv.w * g.w;
      }
    }
    #pragma unroll
    for (int e = 0; e < E_; e++) {
      #pragma unroll
      for (int s = 32; s > 0; s >>= 1) acc[e] += __shfl_xor(acc[e], s);
    }
    if (lane == 0) {
      float logits[E_], sel[E_];
      #pragma unroll
      for (int e = 0; e < E_; e++) {
        logits[e] = 1.f / (1.f + expf(-acc[e]));
        sel[e]    = logits[e] + bias[e];
      }
      int i0 = 0;
      #pragma unroll
      for (int e = 1; e < E_; e++) if (sel[e] > sel[i0]) i0 = e;
      int i1 = (i0 == 0) ? 1 : 0;
      #pragma unroll
      for (int e = 0; e < E_; e++) if (e != i0 && sel[e] > sel[i1]) i1 = e;
      float w0 = logits[i0], w1 = logits[i1], s = w0 + w1;
      top2e[t * 2 + 0] = i0;  top2w[t * 2 + 0] = w0 / s;
      top2e[t * 2 + 1] = i1;  top2w[t * 2 + 1] = w1 / s;
    }
  } else if (b < GATE_BLKS + CONV_BLKS) {
    int i = ((b - GATE_BLKS) * 256 + threadIdx.x) * 4;
    const int n1 = F2_ * H_;
    const float* s; u16* d;
    if (i < n1) { s = sWi + i; d = sWib + i; }
    else        { s = sWo + (i - n1); d = sWob + (i - n1); }
    float4 v = *(const float4*)s;
    ushort4 u;
    u.x = f2bf(v.x); u.y = f2bf(v.y); u.z = f2bf(v.z); u.w = f2bf(v.w);
    *(ushort4*)d = u;
  } else {
    int i = b - (GATE_BLKS + CONV_BLKS);
    int xi = i % TWI_X, yi = (i / TWI_X) % TWI_Y, zi = i / (TWI_X * TWI_Y);
    transpose_core(tile, Wi, WiT, H_, F2_, xi, yi, zi);
  }
}

// ---------------- build lists: 8 blocks (one per expert), zero atomics ----------------
__global__ void build_lists(const int* __restrict__ top2e, const float* __restrict__ top2w,
                            int* __restrict__ counts, int* __restrict__ offs,
                            int* __restrict__ list, float* __restrict__ wlist,
                            int* __restrict__ pos) {
  __shared__ int scnt[4][E_];
  __shared__ int sq[4];
  __shared__ int soffs[E_];
  int e = blockIdx.x;
  int tid = threadIdx.x, w = tid >> 6, lane = tid & 63;
  const int Q = (2 * T_) / 4;   // 2048 per wave-quarter

  int c8[E_];
  #pragma unroll
  for (int q = 0; q < E_; q++) c8[q] = 0;
  for (int i = tid; i < 2 * T_; i += 256) {
    int v = top2e[i];
    #pragma unroll
    for (int q = 0; q < E_; q++) c8[q] += (v == q);
  }
  int qstart = w * Q;
  int ce = 0;
  for (int i = qstart + lane; i < qstart + Q; i += 64) ce += (top2e[i] == e);
  #pragma unroll
  for (int q = 0; q < E_; q++)
    #pragma unroll
    for (int s = 32; s > 0; s >>= 1) c8[q] += __shfl_xor(c8[q], s);
  #pragma unroll
  for (int s = 32; s > 0; s >>= 1) ce += __shfl_xor(ce, s);
  if (lane == 0) {
    #pragma unroll
    for (int q = 0; q < E_; q++) scnt[w][q] = c8[q];
    sq[w] = ce;
  }
  __syncthreads();
  if (tid == 0) {
    int s = 0;
    #pragma unroll
    for (int q = 0; q < E_; q++) {
      int tot = scnt[0][q] + scnt[1][q] + scnt[2][q] + scnt[3][q];
      soffs[q] = s;
      if (e == 0) { counts[q] = tot; offs[q] = s; }
      s += tot;
    }
    if (e == 0) { counts[8] = T_; offs[8] = 2 * T_; }
  }
  __syncthreads();
  int base = soffs[e];
  #pragma unroll
  for (int w2 = 0; w2 < 4; w2++) if (w2 < w) base += sq[w2];
  unsigned long long lt = (lane == 63) ? (~0ull >> 1) : ((1ull << lane) - 1);
  for (int i0 = qstart; i0 < qstart + Q; i0 += 64) {
    int s = i0 + lane;
    bool m = (top2e[s] == e);
    unsigned long long mask = __ballot(m);
    if (m) {
      int p = base + __popcll(mask & lt);
      list[p]  = s >> 1;
      wlist[p] = top2w[s];
      pos[s]   = p;
    }
    base += __popcll(mask);
  }
  for (int t = e * (T_ / 8) + tid; t < (e + 1) * (T_ / 8); t += 256) {
    list[2 * T_ + t]  = t;
    wlist[2 * T_ + t] = 1.f;
  }
}

// ---------------- GEMM1 (+fused SiLU) + Wo-transpose role blocks ----------------
// MEASURED LOCAL OPTIMUM (r8/r11, ~292us total).  128x128 tile, 4 waves, BK=64,
// XOR-swizzled LDS, single-buffer 2-barrier loop, Y-OUTER decode.  Alternatives all
// measured WORSE: dbuf 94.8 (r1), 4blk/CU 77.6 (r2), y-inner 147.5 (r3), BK=128
// 77.4 (r6), counted-vmcnt dbuf 86.0 (r10, correct w/ sched_barrier fencing but
// 64KB LDS + deep window dilutes L2).  Ids >= G1_BLKS run the Wo transpose
// (consumed only by gemm_out_all): they backfill the idle memory pipe as GEMM
// blocks retire.  LDS for the role aliases As.
#define PP1 168   // pairs = 9*18 = 162, padded to multiple of 8
#define G1_BLKS (32 * PP1)   // 5376
__global__ __launch_bounds__(256, 2)
void gemm_act_all(const u16* __restrict__ A, const u16* __restrict__ WiT,
                  const u16* __restrict__ sWib, u16* __restrict__ act,
                  const int* __restrict__ list, const float* __restrict__ wlist,
                  const int* __restrict__ counts, const int* __restrict__ offsets,
                  const float* __restrict__ Wo, u16* __restrict__ WoT) {
  __shared__ __align__(16) u16 As[128 * 64];
  __shared__ __align__(16) u16 Bs[2][64 * 64];

  int id = blockIdx.x;
  if (id >= G1_BLKS) {
    int i = id - G1_BLKS;                  // 0..TWO_BLKS-1
    int xi = i % TWO_X, yi = (i / TWO_X) % TWO_Y, zi = i / (TWO_X * TWO_Y);
    transpose_core((u16(*)[68])As, Wo, WoT, I_, H_, xi, yi, zi);
    return;
  }
  int y  = id / PP1, p = id - y * PP1;     // y-outer: full-work blocks contiguous
  if (p >= 162) return;
  int z = p / 18, xblk = p - z * 18;

  int cnt = counts[z], off = offsets[z];
  int row0 = y * 128;
  if (row0 >= cnt) return;
  const u16* B = (z == 8) ? sWib : (WiT + (long)z * F2_ * H_);
  int n0 = xblk * 64;

  int tid  = threadIdx.x;
  int lane = tid & 63, wv = tid >> 6;
  int wr   = wv >> 1, wc = wv & 1;
  int half = lane & 15, quad = lane >> 4;

  int rA  = tid >> 3;                                // 0..31
  int lc8 = ((tid & 7) ^ (rA & 7)) * 8;              // k-offset within the 64-wide tile
  const u16* ap[4];
  #pragma unroll
  for (int n = 0; n < 4; n++) {
    int rr = min(row0 + rA + n * 32, cnt - 1);
    ap[n] = A + (long)list[off + rr] * H_ + lc8;
  }
  const u16* bp[2][2];
  #pragma unroll
  for (int h = 0; h < 2; h++)
    #pragma unroll
    for (int m = 0; m < 2; m++)
      bp[h][m] = B + (long)(h * I_ + n0 + m * 32 + rA) * H_ + lc8;

  floatx4 acc[2][4][2];
  #pragma unroll
  for (int q = 0; q < 2; q++)
    #pragma unroll
    for (int i = 0; i < 4; i++)
      #pragma unroll
      for (int j = 0; j < 2; j++) acc[q][i][j] = (floatx4)0.f;

  for (int k0 = 0; k0 < H_; k0 += 64) {
    if (k0) __syncthreads();
    #pragma unroll
    for (int n = 0; n < 4; n++) gld16(As + (n * 256 + tid) * 8, ap[n] + k0);
    #pragma unroll
    for (int h = 0; h < 2; h++)
      #pragma unroll
      for (int m = 0; m < 2; m++) gld16(Bs[h] + (m * 256 + tid) * 8, bp[h][m] + k0);
    __syncthreads();
    #pragma unroll
    for (int kk = 0; kk < 2; kk++) {
      int cs = ((kk * 4 + quad) ^ (half & 7)) * 8;   // swizzled chunk offset (u16)
      bf16x8 a[4], bq[2][2];
      #pragma unroll
      for (int i = 0; i < 4; i++)
        a[i] = *(const bf16x8*)(As + (wr * 64 + i * 16 + half) * 64 + cs);
      #pragma unroll
      for (int q = 0; q < 2; q++)
        #pragma unroll
        for (int j = 0; j < 2; j++)
          bq[q][j] = *(const bf16x8*)(Bs[q] + (wc * 32 + j * 16 + half) * 64 + cs);
      #pragma unroll
      for (int i = 0; i < 4; i++)
        #pragma unroll
        for (int q = 0; q < 2; q++)
          #pragma unroll
          for (int j = 0; j < 2; j++)
            acc[q][i][j] = __builtin_amdgcn_mfma_f32_16x16x32_bf16(a[i], bq[q][j], acc[q][i][j], 0, 0, 0);
    }
  }

  bool sh = (z == 8);
  #pragma unroll
  for (int i = 0; i < 4; i++) {
    #pragma unroll
    for (int r = 0; r < 4; r++) {
      int g = row0 + wr * 64 + i * 16 + quad * 4 + r;
      if (g < cnt) {
        float w = wlist[off + g];
        #pragma unroll
        for (int j = 0; j < 2; j++) {
          float va = acc[0][i][j][r];     // first-half col (proj / s_in)
          float vb = acc[1][i][j][r];     // second-half col (gate)
          float zz = sh ? va : vb;        // shared: silu(s_in); expert: silu(gate)
          float o  = sh ? vb : va;
          float sg = zz / (1.f + expf(-zz));
          float v  = sg * o * w;
          int col  = n0 + wc * 32 + j * 16 + half;
          act[(long)(off + g) * I_ + col] = f2bf(v);
        }
      }
    }
  }
}

// ---------------- GEMM2: rows of act @ B^T; expert rows -> bf16 eobuf ----------------
// 64x192 tile, 4 waves (2x2, per-wave 32x96), 32KB LDS, 4 blocks/CU band.
// Expert partial rows stored BF16 (halves eobuf write+read traffic, ~25MB saved);
// shared rows go fp32 straight into out.  atomicAdd fold measured worse (r7).
#define PP2 40    // pairs = 9*4 = 36, padded to multiple of 8
__global__ __launch_bounds__(256, 4)
void gemm_out_all(const u16* __restrict__ A, const u16* __restrict__ WoT,
                  const u16* __restrict__ sWob, float* __restrict__ out,
                  u16* __restrict__ eobuf,
                  const int* __restrict__ counts, const int* __restrict__ offsets) {
  __shared__ __align__(16) u16 As[64 * 64];    //  8 KB
  __shared__ __align__(16) u16 Bs[192 * 64];   // 24 KB

  int id = blockIdx.x;
  int y  = id / PP2, p = id - y * PP2;
  if (p >= 36) return;
  int z = p / 4, xblk = p - z * 4;

  int cnt = counts[z], off = offsets[z];
  int row0 = y * 64;
  if (row0 >= cnt) return;
  const u16* B = (z == 8) ? sWob : (WoT + (long)z * H_ * I_);
  int n0 = xblk * 192;

  int tid  = threadIdx.x;
  int lane = tid & 63, wv = tid >> 6;
  int wr   = wv >> 1, wc = wv & 1;
  int half = lane & 15, quad = lane >> 4;

  int rA  = tid >> 3;                            // 0..31
  int lc8 = ((tid & 7) ^ (rA & 7)) * 8;
  const u16* ap[2];
  #pragma unroll
  for (int n = 0; n < 2; n++) {
    long rr = off + min(row0 + rA + n * 32, cnt - 1);
    ap[n] = A + rr * I_ + lc8;
  }
  const u16* bp[6];
  #pragma unroll
  for (int m = 0; m < 6; m++)
    bp[m] = B + (long)(n0 + m * 32 + rA) * I_ + lc8;

  floatx4 acc[2][6];
  #pragma unroll
  for (int i = 0; i < 2; i++)
    #pragma unroll
    for (int j = 0; j < 6; j++) acc[i][j] = (floatx4)0.f;

  for (int k0 = 0; k0 < I_; k0 += 64) {          // 18 iterations
    if (k0) __syncthreads();
    #pragma unroll
    for (int n = 0; n < 2; n++) gld16(As + (n * 256 + tid) * 8, ap[n] + k0);
    #pragma unroll
    for (int m = 0; m < 6; m++) gld16(Bs + (m * 256 + tid) * 8, bp[m] + k0);
    __syncthreads();
    #pragma unroll
    for (int kk = 0; kk < 2; kk++) {
      int cs = ((kk * 4 + quad) ^ (half & 7)) * 8;
      bf16x8 a[2], b[6];
      #pragma unroll
      for (int i = 0; i < 2; i++)
        a[i] = *(const bf16x8*)(As + (wr * 32 + i * 16 + half) * 64 + cs);
      #pragma unroll
      for (int j = 0; j < 6; j++)
        b[j] = *(const bf16x8*)(Bs + (wc * 96 + j * 16 + half) * 64 + cs);
      #pragma unroll
      for (int i = 0; i < 2; i++)
        #pragma unroll
        for (int j = 0; j < 6; j++)
          acc[i][j] = __builtin_amdgcn_mfma_f32_16x16x32_bf16(a[i], b[j], acc[i][j], 0, 0, 0);
    }
  }

  bool sh = (z == 8);
  #pragma unroll
  for (int i = 0; i < 2; i++) {
    #pragma unroll
    for (int r = 0; r < 4; r++) {
      int g = row0 + wr * 32 + i * 16 + quad * 4 + r;
      if (g < cnt) {
        #pragma unroll
        for (int j = 0; j < 6; j++) {
          int col = n0 + wc * 96 + j * 16 + half;
          if (sh) out[(long)g * H_ + col] = acc[i][j][r];
          else    eobuf[(long)(off + g) * H_ + col] = f2bf(acc[i][j][r]);
        }
      }
    }
  }
}

// ---------------- final: out[t] += bf2f(eobuf[pos0[t]]) + bf2f(eobuf[pos1[t]]) -------
__global__ void final_reduce(float* __restrict__ out, const u16* __restrict__ eobuf,
                             const int* __restrict__ pos) {
  int gid = blockIdx.x * 256 + threadIdx.x;
  int t = gid / (H_ / 4), c = (gid % (H_ / 4)) * 4;
  int p0 = pos[t * 2], p1 = pos[t * 2 + 1];
  float4 a  = *(const float4*)(out + (long)t * H_ + c);
  ushort4 b = *(const ushort4*)(eobuf + (long)p0 * H_ + c);
  ushort4 d = *(const ushort4*)(eobuf + (long)p1 * H_ + c);
  a.x += bf2f(b.x) + bf2f(d.x);
  a.y += bf2f(b.y) + bf2f(d.y);
  a.z += bf2f(b.z) + bf2f(d.z);
  a.w += bf2f(b.w) + bf2f(d.w);
  *(float4*)(out + (long)t * H_ + c) = a;
}

extern "C" void kernel_launch(void* const* d_in, const int* in_sizes, int n_in,
                              void* d_out, int out_size, void* d_ws, size_t ws_size,
                              hipStream_t stream) {
  const float* x      = (const float*)d_in[0];
  const float* gate_w = (const float*)d_in[1];
  const float* bias   = (const float*)d_in[2];
  const float* Wi     = (const float*)d_in[3];
  const float* Wo     = (const float*)d_in[4];
  const float* sWi    = (const float*)d_in[5];
  const float* sWo    = (const float*)d_in[6];
  float* out          = (float*)d_out;

  char* ws = (char*)d_ws;
  size_t o = 0;
  auto alloc = [&](size_t bytes) -> void* {
    o = (o + 255) & ~(size_t)255;
    void* p = ws + o;
    o += bytes;
    return p;
  };
  u16*   xb    = (u16*)  alloc((size_t)T_ * H_ * 2);
  u16*   sWib  = (u16*)  alloc((size_t)F2_ * H_ * 2);
  u16*   sWob  = (u16*)  alloc((size_t)H_ * I_ * 2);
  u16*   WiT   = (u16*)  alloc((size_t)E_ * F2_ * H_ * 2);   // 28.3 MB
  u16*   WoT   = (u16*)  alloc((size_t)E_ * H_ * I_ * 2);
  u16*   act   = (u16*)  alloc((size_t)3 * T_ * I_ * 2);
  int*   top2e = (int*)  alloc((size_t)T_ * 2 * 4);
  float* top2w = (float*)alloc((size_t)T_ * 2 * 4);
  int*   count = (int*)  alloc(9 * 4);
  int*   offs  = (int*)  alloc(9 * 4);
  int*   list  = (int*)  alloc((size_t)3 * T_ * 4);
  float* wlist = (float*)alloc((size_t)3 * T_ * 4);
  int*   pos   = (int*)  alloc((size_t)2 * T_ * 4);
  // eobuf bf16 (8192*768*2 = 12.6 MB) aliases WiT (28.3 MB): WiT dead after gemm_act_all.
  u16* eobuf = (u16*)WiT;

  prep_all<<<PREP_BLKS, 256, 0, stream>>>(x, gate_w, bias, top2e, top2w, xb,
                                          sWi, sWib, sWo, sWob, Wi, WiT);
  build_lists<<<E_, 256, 0, stream>>>(top2e, top2w, count, offs, list, wlist, pos);

  gemm_act_all<<<G1_BLKS + TWO_BLKS, 256, 0, stream>>>(xb, WiT, sWib, act, list, wlist,
                                                       count, offs, Wo, WoT);
  gemm_out_all<<<64 * PP2, 256, 0, stream>>>(act, WoT, sWob, out, eobuf, count, offs);
  final_reduce<<<(T_ * (H_ / 4)) / 256, 256, 0, stream>>>(out, eobuf, pos);
}

// Round 13
// 288.547 us; speedup vs baseline: 1.0384x; 1.0384x over previous
//
#include <hip/hip_runtime.h>
#include <stdint.h>

#define E_  8
#define H_  768
#define I_  1152
#define T_  4096
#define F2_ (2*I_)   // 2304

typedef unsigned short u16;
typedef __attribute__((ext_vector_type(8))) __bf16 bf16x8;
typedef __attribute__((ext_vector_type(4))) float floatx4;

typedef const void __attribute__((address_space(1))) as1_void;
typedef void __attribute__((address_space(3))) as3_void;

__device__ __forceinline__ void gld16(void* lds, const void* g) {
  __builtin_amdgcn_global_load_lds((as1_void*)g, (as3_void*)lds, 16, 0, 0);
}

__device__ __forceinline__ u16 f2bf(float f) {
  union { float f; unsigned int i; } v; v.f = f;
  unsigned int r = v.i + 0x7FFF + ((v.i >> 16) & 1);  // round-to-nearest-even
  return (u16)(r >> 16);
}

// Vectorized transpose+convert core (G13): float4 reads, ushort4 LDS writes (pad 68
// keeps 8B row alignment), ushort4 global stores.  Caller provides the LDS tile.
__device__ __forceinline__ void transpose_core(u16 (*tile)[68],
                                               const float* __restrict__ src,
                                               u16* __restrict__ dst,
                                               int R, int C, int xi, int yi, int zi) {
  const float* s = src + (long)zi * R * C;
  u16*         d = dst + (long)zi * R * C;
  int r0 = yi * 64, c0 = xi * 64;
  int c4 = (threadIdx.x & 15) * 4;        // col offset 0..60
  int rr = threadIdx.x >> 4;              // row 0..15
  #pragma unroll
  for (int k = 0; k < 64; k += 16) {
    float4 v = *(const float4*)(s + (long)(r0 + rr + k) * C + (c0 + c4));
    ushort4 u;
    u.x = f2bf(v.x); u.y = f2bf(v.y); u.z = f2bf(v.z); u.w = f2bf(v.w);
    *(ushort4*)&tile[rr + k][c4] = u;
  }
  __syncthreads();
  int c  = threadIdx.x >> 2;              // 0..63
  int rq = (threadIdx.x & 3) * 4;         // 0,4,8,12
  #pragma unroll
  for (int k = 0; k < 64; k += 16) {
    ushort4 u;
    u.x = tile[rq + k + 0][c];
    u.y = tile[rq + k + 1][c];
    u.z = tile[rq + k + 2][c];
    u.w = tile[rq + k + 3][c];
    *(ushort4*)(d + (long)(c0 + c) * R + (r0 + rq + k)) = u;
  }
}

// ====== fused prep: gate + convert sWi/sWo + transpose Wi (Wo transpose lives in g1) ===
#define GATE_BLKS (T_ / 4)                              // 1024
#define CONV_BLKS ((F2_ * H_ + H_ * I_) / 1024)         // 2592
#define TWI_X (F2_ / 64)                                // 36
#define TWI_Y (H_ / 64)                                 // 12
#define TWI_BLKS (TWI_X * TWI_Y * E_)                   // 3456
#define TWO_X (H_ / 64)                                 // 12
#define TWO_Y (I_ / 64)                                 // 18
#define TWO_BLKS (TWO_X * TWO_Y * E_)                   // 1728 (runs inside g1's grid)
#define PREP_BLKS (GATE_BLKS + CONV_BLKS + TWI_BLKS)

__global__ __launch_bounds__(256)
void prep_all(const float* __restrict__ x, const float* __restrict__ gw,
              const float* __restrict__ bias,
              int* __restrict__ top2e, float* __restrict__ top2w, u16* __restrict__ xb,
              const float* __restrict__ sWi, u16* __restrict__ sWib,
              const float* __restrict__ sWo, u16* __restrict__ sWob,
              const float* __restrict__ Wi, u16* __restrict__ WiT) {
  __shared__ u16 tile[64][68];
  int b = blockIdx.x;
  if (b < GATE_BLKS) {
    int t    = b * 4 + (threadIdx.x >> 6);
    int lane = threadIdx.x & 63;
    float acc[E_];
    #pragma unroll
    for (int e = 0; e < E_; e++) acc[e] = 0.f;
    #pragma unroll
    for (int i = 0; i < H_ / 256; i++) {
      int c = i * 256 + lane * 4;
      float4 xv = *(const float4*)(x + (long)t * H_ + c);
      ushort4 u;
      u.x = f2bf(xv.x); u.y = f2bf(xv.y); u.z = f2bf(xv.z); u.w = f2bf(xv.w);
      *(ushort4*)(xb + (long)t * H_ + c) = u;
      #pragma unroll
      for (int e = 0; e < E_; e++) {
        float4 g = *(const float4*)(gw + e * H_ + c);
        acc[e] += xv.x * g.x + xv.y * g.y + xv.z * g.z + xv.w * g.w;
      }
    }
    #pragma unroll
    for (int e = 0; e < E_; e++) {
      #pragma unroll
      for (int s = 32; s > 0; s >>= 1) acc[e] += __shfl_xor(acc[e], s);
    }
    if (lane == 0) {
      float logits[E_], sel[E_];
      #pragma unroll
      for (int e = 0; e < E_; e++) {
        logits[e] = 1.f / (1.f + expf(-acc[e]));
        sel[e]    = logits[e] + bias[e];
      }
      int i0 = 0;
      #pragma unroll
      for (int e = 1; e < E_; e++) if (sel[e] > sel[i0]) i0 = e;
      int i1 = (i0 == 0) ? 1 : 0;
      #pragma unroll
      for (int e = 0; e < E_; e++) if (e != i0 && sel[e] > sel[i1]) i1 = e;
      float w0 = logits[i0], w1 = logits[i1], s = w0 + w1;
      top2e[t * 2 + 0] = i0;  top2w[t * 2 + 0] = w0 / s;
      top2e[t * 2 + 1] = i1;  top2w[t * 2 + 1] = w1 / s;
    }
  } else if (b < GATE_BLKS + CONV_BLKS) {
    int i = ((b - GATE_BLKS) * 256 + threadIdx.x) * 4;
    const int n1 = F2_ * H_;
    const float* s; u16* d;
    if (i < n1) { s = sWi + i; d = sWib + i; }
    else        { s = sWo + (i - n1); d = sWob + (i - n1); }
    float4 v = *(const float4*)s;
    ushort4 u;
    u.x = f2bf(v.x); u.y = f2bf(v.y); u.z = f2bf(v.z); u.w = f2bf(v.w);
    *(ushort4*)d = u;
  } else {
    int i = b - (GATE_BLKS + CONV_BLKS);
    int xi = i % TWI_X, yi = (i / TWI_X) % TWI_Y, zi = i / (TWI_X * TWI_Y);
    transpose_core(tile, Wi, WiT, H_, F2_, xi, yi, zi);
  }
}

// ---------------- build lists: 8 blocks (one per expert), zero atomics ----------------
__global__ void build_lists(const int* __restrict__ top2e, const float* __restrict__ top2w,
                            int* __restrict__ counts, int* __restrict__ offs,
                            int* __restrict__ list, float* __restrict__ wlist,
                            int* __restrict__ pos) {
  __shared__ int scnt[4][E_];
  __shared__ int sq[4];
  __shared__ int soffs[E_];
  int e = blockIdx.x;
  int tid = threadIdx.x, w = tid >> 6, lane = tid & 63;
  const int Q = (2 * T_) / 4;   // 2048 per wave-quarter

  int c8[E_];
  #pragma unroll
  for (int q = 0; q < E_; q++) c8[q] = 0;
  for (int i = tid; i < 2 * T_; i += 256) {
    int v = top2e[i];
    #pragma unroll
    for (int q = 0; q < E_; q++) c8[q] += (v == q);
  }
  int qstart = w * Q;
  int ce = 0;
  for (int i = qstart + lane; i < qstart + Q; i += 64) ce += (top2e[i] == e);
  #pragma unroll
  for (int q = 0; q < E_; q++)
    #pragma unroll
    for (int s = 32; s > 0; s >>= 1) c8[q] += __shfl_xor(c8[q], s);
  #pragma unroll
  for (int s = 32; s > 0; s >>= 1) ce += __shfl_xor(ce, s);
  if (lane == 0) {
    #pragma unroll
    for (int q = 0; q < E_; q++) scnt[w][q] = c8[q];
    sq[w] = ce;
  }
  __syncthreads();
  if (tid == 0) {
    int s = 0;
    #pragma unroll
    for (int q = 0; q < E_; q++) {
      int tot = scnt[0][q] + scnt[1][q] + scnt[2][q] + scnt[3][q];
      soffs[q] = s;
      if (e == 0) { counts[q] = tot; offs[q] = s; }
      s += tot;
    }
    if (e == 0) { counts[8] = T_; offs[8] = 2 * T_; }
  }
  __syncthreads();
  int base = soffs[e];
  #pragma unroll
  for (int w2 = 0; w2 < 4; w2++) if (w2 < w) base += sq[w2];
  unsigned long long lt = (lane == 63) ? (~0ull >> 1) : ((1ull << lane) - 1);
  for (int i0 = qstart; i0 < qstart + Q; i0 += 64) {
    int s = i0 + lane;
    bool m = (top2e[s] == e);
    unsigned long long mask = __ballot(m);
    if (m) {
      int p = base + __popcll(mask & lt);
      list[p]  = s >> 1;
      wlist[p] = top2w[s];
      pos[s]   = p;
    }
    base += __popcll(mask);
  }
  for (int t = e * (T_ / 8) + tid; t < (e + 1) * (T_ / 8); t += 256) {
    list[2 * T_ + t]  = t;
    wlist[2 * T_ + t] = 1.f;
  }
}

// ---------------- GEMM1 (+fused SiLU) + Wo-transpose role blocks ----------------
// MEASURED BEST (r8: 291.7us, r11: 292.2us total; g1 ~73-78us, MfmaUtil ~24%).
// 128x128 tile, 4 waves, BK=64, XOR-swizzled LDS, single-buffer 2-barrier loop,
// Y-OUTER decode.  Full falsified ledger on this kernel:
//   dbuf+__syncthreads      94.8us (r1)    4 blocks/CU (64x128)  77.6us (r2)
//   y-inner decode         147.5us (r3)    BK=128                77.4us (r6)
//   counted-vmcnt dbuf      86.0us (r10, correct w/ fencing; LDS/L2 cost)
//   bf16 eobuf (g2 side)   +7.4us total (r12: narrow stores + f2bf on store path)
// Ids >= G1_BLKS run the Wo transpose (consumed only by gemm_out_all): they
// backfill the idle memory pipe as GEMM blocks retire.  LDS aliases As.
#define PP1 168   // pairs = 9*18 = 162, padded to multiple of 8
#define G1_BLKS (32 * PP1)   // 5376
__global__ __launch_bounds__(256, 2)
void gemm_act_all(const u16* __restrict__ A, const u16* __restrict__ WiT,
                  const u16* __restrict__ sWib, u16* __restrict__ act,
                  const int* __restrict__ list, const float* __restrict__ wlist,
                  const int* __restrict__ counts, const int* __restrict__ offsets,
                  const float* __restrict__ Wo, u16* __restrict__ WoT) {
  __shared__ __align__(16) u16 As[128 * 64];
  __shared__ __align__(16) u16 Bs[2][64 * 64];

  int id = blockIdx.x;
  if (id >= G1_BLKS) {
    int i = id - G1_BLKS;                  // 0..TWO_BLKS-1
    int xi = i % TWO_X, yi = (i / TWO_X) % TWO_Y, zi = i / (TWO_X * TWO_Y);
    transpose_core((u16(*)[68])As, Wo, WoT, I_, H_, xi, yi, zi);
    return;
  }
  int y  = id / PP1, p = id - y * PP1;     // y-outer: full-work blocks contiguous
  if (p >= 162) return;
  int z = p / 18, xblk = p - z * 18;

  int cnt = counts[z], off = offsets[z];
  int row0 = y * 128;
  if (row0 >= cnt) return;
  const u16* B = (z == 8) ? sWib : (WiT + (long)z * F2_ * H_);
  int n0 = xblk * 64;

  int tid  = threadIdx.x;
  int lane = tid & 63, wv = tid >> 6;
  int wr   = wv >> 1, wc = wv & 1;
  int half = lane & 15, quad = lane >> 4;

  int rA  = tid >> 3;                                // 0..31
  int lc8 = ((tid & 7) ^ (rA & 7)) * 8;              // k-offset within the 64-wide tile
  const u16* ap[4];
  #pragma unroll
  for (int n = 0; n < 4; n++) {
    int rr = min(row0 + rA + n * 32, cnt - 1);
    ap[n] = A + (long)list[off + rr] * H_ + lc8;
  }
  const u16* bp[2][2];
  #pragma unroll
  for (int h = 0; h < 2; h++)
    #pragma unroll
    for (int m = 0; m < 2; m++)
      bp[h][m] = B + (long)(h * I_ + n0 + m * 32 + rA) * H_ + lc8;

  floatx4 acc[2][4][2];
  #pragma unroll
  for (int q = 0; q < 2; q++)
    #pragma unroll
    for (int i = 0; i < 4; i++)
      #pragma unroll
      for (int j = 0; j < 2; j++) acc[q][i][j] = (floatx4)0.f;

  for (int k0 = 0; k0 < H_; k0 += 64) {
    if (k0) __syncthreads();
    #pragma unroll
    for (int n = 0; n < 4; n++) gld16(As + (n * 256 + tid) * 8, ap[n] + k0);
    #pragma unroll
    for (int h = 0; h < 2; h++)
      #pragma unroll
      for (int m = 0; m < 2; m++) gld16(Bs[h] + (m * 256 + tid) * 8, bp[h][m] + k0);
    __syncthreads();
    #pragma unroll
    for (int kk = 0; kk < 2; kk++) {
      int cs = ((kk * 4 + quad) ^ (half & 7)) * 8;   // swizzled chunk offset (u16)
      bf16x8 a[4], bq[2][2];
      #pragma unroll
      for (int i = 0; i < 4; i++)
        a[i] = *(const bf16x8*)(As + (wr * 64 + i * 16 + half) * 64 + cs);
      #pragma unroll
      for (int q = 0; q < 2; q++)
        #pragma unroll
        for (int j = 0; j < 2; j++)
          bq[q][j] = *(const bf16x8*)(Bs[q] + (wc * 32 + j * 16 + half) * 64 + cs);
      #pragma unroll
      for (int i = 0; i < 4; i++)
        #pragma unroll
        for (int q = 0; q < 2; q++)
          #pragma unroll
          for (int j = 0; j < 2; j++)
            acc[q][i][j] = __builtin_amdgcn_mfma_f32_16x16x32_bf16(a[i], bq[q][j], acc[q][i][j], 0, 0, 0);
    }
  }

  bool sh = (z == 8);
  #pragma unroll
  for (int i = 0; i < 4; i++) {
    #pragma unroll
    for (int r = 0; r < 4; r++) {
      int g = row0 + wr * 64 + i * 16 + quad * 4 + r;
      if (g < cnt) {
        float w = wlist[off + g];
        #pragma unroll
        for (int j = 0; j < 2; j++) {
          float va = acc[0][i][j][r];     // first-half col (proj / s_in)
          float vb = acc[1][i][j][r];     // second-half col (gate)
          float zz = sh ? va : vb;        // shared: silu(s_in); expert: silu(gate)
          float o  = sh ? vb : va;
          float sg = zz / (1.f + expf(-zz));
          float v  = sg * o * w;
          int col  = n0 + wc * 32 + j * 16 + half;
          act[(long)(off + g) * I_ + col] = f2bf(v);
        }
      }
    }
  }
}

// ---------------- GEMM2: rows of act @ B^T, plain fp32 stores (measured-best) --------
// 64x192 tile, 4 waves (2x2, per-wave 32x96), 32KB LDS, 4 blocks/CU band.
// atomicAdd fold worse (r7); bf16 eobuf worse (r12).
#define PP2 40    // pairs = 9*4 = 36, padded to multiple of 8
__global__ __launch_bounds__(256, 4)
void gemm_out_all(const u16* __restrict__ A, const u16* __restrict__ WoT,
                  const u16* __restrict__ sWob, float* __restrict__ out,
                  float* __restrict__ eobuf,
                  const int* __restrict__ counts, const int* __restrict__ offsets) {
  __shared__ __align__(16) u16 As[64 * 64];    //  8 KB
  __shared__ __align__(16) u16 Bs[192 * 64];   // 24 KB

  int id = blockIdx.x;
  int y  = id / PP2, p = id - y * PP2;
  if (p >= 36) return;
  int z = p / 4, xblk = p - z * 4;

  int cnt = counts[z], off = offsets[z];
  int row0 = y * 64;
  if (row0 >= cnt) return;
  const u16* B = (z == 8) ? sWob : (WoT + (long)z * H_ * I_);
  int n0 = xblk * 192;

  int tid  = threadIdx.x;
  int lane = tid & 63, wv = tid >> 6;
  int wr   = wv >> 1, wc = wv & 1;
  int half = lane & 15, quad = lane >> 4;

  int rA  = tid >> 3;                            // 0..31
  int lc8 = ((tid & 7) ^ (rA & 7)) * 8;
  const u16* ap[2];
  #pragma unroll
  for (int n = 0; n < 2; n++) {
    long rr = off + min(row0 + rA + n * 32, cnt - 1);
    ap[n] = A + rr * I_ + lc8;
  }
  const u16* bp[6];
  #pragma unroll
  for (int m = 0; m < 6; m++)
    bp[m] = B + (long)(n0 + m * 32 + rA) * I_ + lc8;

  floatx4 acc[2][6];
  #pragma unroll
  for (int i = 0; i < 2; i++)
    #pragma unroll
    for (int j = 0; j < 6; j++) acc[i][j] = (floatx4)0.f;

  for (int k0 = 0; k0 < I_; k0 += 64) {          // 18 iterations
    if (k0) __syncthreads();
    #pragma unroll
    for (int n = 0; n < 2; n++) gld16(As + (n * 256 + tid) * 8, ap[n] + k0);
    #pragma unroll
    for (int m = 0; m < 6; m++) gld16(Bs + (m * 256 + tid) * 8, bp[m] + k0);
    __syncthreads();
    #pragma unroll
    for (int kk = 0; kk < 2; kk++) {
      int cs = ((kk * 4 + quad) ^ (half & 7)) * 8;
      bf16x8 a[2], b[6];
      #pragma unroll
      for (int i = 0; i < 2; i++)
        a[i] = *(const bf16x8*)(As + (wr * 32 + i * 16 + half) * 64 + cs);
      #pragma unroll
      for (int j = 0; j < 6; j++)
        b[j] = *(const bf16x8*)(Bs + (wc * 96 + j * 16 + half) * 64 + cs);
      #pragma unroll
      for (int i = 0; i < 2; i++)
        #pragma unroll
        for (int j = 0; j < 6; j++)
          acc[i][j] = __builtin_amdgcn_mfma_f32_16x16x32_bf16(a[i], b[j], acc[i][j], 0, 0, 0);
    }
  }

  bool sh = (z == 8);
  #pragma unroll
  for (int i = 0; i < 2; i++) {
    #pragma unroll
    for (int r = 0; r < 4; r++) {
      int g = row0 + wr * 32 + i * 16 + quad * 4 + r;
      if (g < cnt) {
        float* orow = sh ? (out + (long)g * H_) : (eobuf + (long)(off + g) * H_);
        #pragma unroll
        for (int j = 0; j < 6; j++) {
          int col = n0 + wc * 96 + j * 16 + half;
          orow[col] = acc[i][j][r];
        }
      }
    }
  }
}

// ---------------- final: out[t] += eobuf[pos0[t]] + eobuf[pos1[t]] ----------------
__global__ void final_reduce(float* __restrict__ out, const float* __restrict__ eobuf,
                             const int* __restrict__ pos) {
  int gid = blockIdx.x * 256 + threadIdx.x;
  int t = gid / (H_ / 4), c = (gid % (H_ / 4)) * 4;
  int p0 = pos[t * 2], p1 = pos[t * 2 + 1];
  float4 a = *(const float4*)(out   + (long)t  * H_ + c);
  float4 b = *(const float4*)(eobuf + (long)p0 * H_ + c);
  float4 d = *(const float4*)(eobuf + (long)p1 * H_ + c);
  a.x += b.x + d.x; a.y += b.y + d.y; a.z += b.z + d.z; a.w += b.w + d.w;
  *(float4*)(out + (long)t * H_ + c) = a;
}

extern "C" void kernel_launch(void* const* d_in, const int* in_sizes, int n_in,
                              void* d_out, int out_size, void* d_ws, size_t ws_size,
                              hipStream_t stream) {
  const float* x      = (const float*)d_in[0];
  const float* gate_w = (const float*)d_in[1];
  const float* bias   = (const float*)d_in[2];
  const float* Wi     = (const float*)d_in[3];
  const float* Wo     = (const float*)d_in[4];
  const float* sWi    = (const float*)d_in[5];
  const float* sWo    = (const float*)d_in[6];
  float* out          = (float*)d_out;

  char* ws = (char*)d_ws;
  size_t o = 0;
  auto alloc = [&](size_t bytes) -> void* {
    o = (o + 255) & ~(size_t)255;
    void* p = ws + o;
    o += bytes;
    return p;
  };
  u16*   xb    = (u16*)  alloc((size_t)T_ * H_ * 2);
  u16*   sWib  = (u16*)  alloc((size_t)F2_ * H_ * 2);
  u16*   sWob  = (u16*)  alloc((size_t)H_ * I_ * 2);
  u16*   WiT   = (u16*)  alloc((size_t)E_ * F2_ * H_ * 2);   // 28.3 MB
  u16*   WoT   = (u16*)  alloc((size_t)E_ * H_ * I_ * 2);
  u16*   act   = (u16*)  alloc((size_t)3 * T_ * I_ * 2);
  int*   top2e = (int*)  alloc((size_t)T_ * 2 * 4);
  float* top2w = (float*)alloc((size_t)T_ * 2 * 4);
  int*   count = (int*)  alloc(9 * 4);
  int*   offs  = (int*)  alloc(9 * 4);
  int*   list  = (int*)  alloc((size_t)3 * T_ * 4);
  float* wlist = (float*)alloc((size_t)3 * T_ * 4);
  int*   pos   = (int*)  alloc((size_t)2 * T_ * 4);
  // eobuf (8192*768*4 = 25.2 MB) aliases WiT (28.3 MB): WiT dead after gemm_act_all.
  float* eobuf = (float*)WiT;

  prep_all<<<PREP_BLKS, 256, 0, stream>>>(x, gate_w, bias, top2e, top2w, xb,
                                          sWi, sWib, sWo, sWob, Wi, WiT);
  build_lists<<<E_, 256, 0, stream>>>(top2e, top2w, count, offs, list, wlist, pos);

  gemm_act_all<<<G1_BLKS + TWO_BLKS, 256, 0, stream>>>(xb, WiT, sWib, act, list, wlist,
                                                       count, offs, Wo, WoT);
  gemm_out_all<<<64 * PP2, 256, 0, stream>>>(act, WoT, sWob, out, eobuf, count, offs);
  final_reduce<<<(T_ * (H_ / 4)) / 256, 256, 0, stream>>>(out, eobuf, pos);
}